// Round 14
// baseline (269.689 us; speedup 1.0000x reference)
//
#include <hip/hip_runtime.h>
#include <hip/hip_bf16.h>

// Problem constants (from reference)
#define NN 50000
#define EE 100000
#define GG 2048
#define NB2 391   // ceil(2*NN/256) for the dual (dst|src) scan

typedef float v2f __attribute__((ext_vector_type(2)));
__device__ __forceinline__ v2f fma2(v2f a, float b, v2f c) {
    return __builtin_elementwise_fma(a, (v2f){b, b}, c);
}

__device__ __forceinline__ float b2f(unsigned short u) {
    union { unsigned int i; float f; } x; x.i = (unsigned int)u << 16; return x.f;
}
__device__ __forceinline__ unsigned short f2b(float f) {
    union { float f; unsigned int i; } x; x.f = f;
    unsigned int b = x.i + (0x7FFFu + ((x.i >> 16) & 1u));   // RNE
    return (unsigned short)(b >> 16);
}

// Fused setup: blocks [0,6249] init feat; [6250,6277] build weight tables;
// [6278,6668] degree histogram.
__global__ __launch_bounds__(256) void k_setup(
    const float* __restrict__ x, const float* __restrict__ lw,
    const float* __restrict__ lb, const float* __restrict__ nnw,
    const float* __restrict__ nnb, const float* __restrict__ rootw,
    const float* __restrict__ wi, const float* __restrict__ wh,
    const int* __restrict__ ei, float* __restrict__ feat,
    float* __restrict__ Wre, float4* __restrict__ rw4,
    float4* __restrict__ wi4, int* __restrict__ cnt) {
    int blk = blockIdx.x;
    int t = threadIdx.x;
    if (blk < 6250) {
        int idx = blk * 256 + t;
        if (idx >= NN * 32) return;
        int n = idx >> 5, o = idx & 31;
        const float* xr = x + n * 11;
        const float* wr = lw + o * 11;
        float acc = lb[o];
#pragma unroll
        for (int i = 0; i < 11; ++i) acc += xr[i] * wr[i];
        feat[idx] = fmaxf(acc, 0.f);
    } else if (blk < 6278) {
        int idx = (blk - 6250) * 256 + t;
        if (idx < 5120) {
            int c = idx >> 5, i = idx & 31;
            float v;
            if (c < 128) v = nnw[((i << 5) + (c & 31)) * 4 + (c >> 5)];
            else         v = nnb[(i << 5) + (c - 128)];
            Wre[idx] = v;
        } else if (idx < 6144) {
            int j = idx - 5120;
            int k = j >> 5, o = j & 31;
            rw4[j] = make_float4(rootw[k * 32 + o], wh[o * 32 + k],
                                 wh[(32 + o) * 32 + k], wh[(64 + o) * 32 + k]);
        } else if (idx < 7168) {
            int j = idx - 6144;
            int k = j >> 5, o = j & 31;
            wi4[j] = make_float4(wi[o * 32 + k], wi[(32 + o) * 32 + k],
                                 wi[(64 + o) * 32 + k], 0.f);
        }
    } else {
        int e = (blk - 6278) * 256 + t;
        if (e >= EE) return;
        atomicAdd(&cnt[ei[EE + e]], 1);
        atomicAdd(&cnt[NN + ei[e]], 1);
    }
}

__global__ __launch_bounds__(256) void k_scan1(const int* __restrict__ cnt,
                                               int* __restrict__ tmp,
                                               int* __restrict__ bsum) {
    __shared__ int sd[256];
    int t = threadIdx.x;
    int i = blockIdx.x * 256 + t;
    int v = (i < 2 * NN) ? cnt[i] : 0;
    sd[t] = v;
    __syncthreads();
#pragma unroll
    for (int off = 1; off < 256; off <<= 1) {
        int x = (t >= off) ? sd[t - off] : 0;
        __syncthreads();
        sd[t] += x;
        __syncthreads();
    }
    if (i < 2 * NN) tmp[i] = sd[t];
    if (t == 255) bsum[blockIdx.x] = sd[255];
}

__global__ __launch_bounds__(512) void k_scan2(int* __restrict__ bsum) {
    __shared__ int sd[512];
    int t = threadIdx.x;
    int v = (t < NB2) ? bsum[t] : 0;
    sd[t] = v;
    __syncthreads();
#pragma unroll
    for (int off = 1; off < 512; off <<= 1) {
        int x = (t >= off) ? sd[t - off] : 0;
        __syncthreads();
        sd[t] += x;
        __syncthreads();
    }
    if (t < NB2) bsum[t] = sd[t];
}

__global__ void k_scan3(const int* __restrict__ cnt, const int* __restrict__ tmp,
                        const int* __restrict__ bsum, int* __restrict__ row_ptr,
                        int* __restrict__ cursor, int* __restrict__ out_ptr,
                        int* __restrict__ cursor2) {
    int i = blockIdx.x * blockDim.x + threadIdx.x;
    if (i >= 2 * NN) return;
    int base = (blockIdx.x > 0) ? bsum[blockIdx.x - 1] : 0;
    int excl = base + tmp[i] - cnt[i];
    if (i < NN) {
        row_ptr[i] = excl;
        cursor[i] = excl;
        if (i == 0) row_ptr[NN] = EE;
    } else {
        int j = i - NN;
        out_ptr[j] = excl - EE;
        cursor2[j] = excl - EE;
        if (j == 0) out_ptr[NN] = EE;
    }
}

// Fused: blocks [0,390] scatter edges into CSR/CSC; blocks [391, 391+3127]
// compute the initial y table (on k_setup's feat).
__global__ __launch_bounds__(256) void k_scatter_y(
    const int* __restrict__ ei, const float* __restrict__ ea,
    int* __restrict__ cursor, int* __restrict__ cursor2,
    int* __restrict__ esrc, float4* __restrict__ eea,
    int* __restrict__ oslot, float4* __restrict__ oea,
    const float* __restrict__ feat, const float* __restrict__ Wre,
    unsigned short* __restrict__ yb) {
    int blk = blockIdx.x;
    if (blk < 391) {
        int e = blk * 256 + threadIdx.x;
        if (e >= EE) return;
        int s = ei[e], d = ei[EE + e];
        float4 a = make_float4(ea[e * 4 + 0], ea[e * 4 + 1], ea[e * 4 + 2], ea[e * 4 + 3]);
        int slot = atomicAdd(&cursor[d], 1);
        esrc[slot] = s;
        eea[slot] = a;
        int pos = atomicAdd(&cursor2[s], 1);
        oslot[pos] = slot;
        oea[pos] = a;
        return;
    }
    int by = blk - 391;
    int bx = by % 782, q = by / 782;
    int lane = threadIdx.x & 63;
    int wv = __builtin_amdgcn_readfirstlane(threadIdx.x >> 6);
    int n = bx * 64 + lane;
    if (n >= NN) return;
    int c0 = q * 40 + wv * 10;
    float fr[32];
    const float4* f4 = (const float4*)(feat + (long)n * 32);
#pragma unroll
    for (int qq = 0; qq < 8; ++qq) {
        float4 v = f4[qq];
        fr[4 * qq + 0] = v.x; fr[4 * qq + 1] = v.y;
        fr[4 * qq + 2] = v.z; fr[4 * qq + 3] = v.w;
    }
    float acc[10];
#pragma unroll
    for (int cc = 0; cc < 10; ++cc) {
        const float* w = Wre + (c0 + cc) * 32;   // uniform address -> s_load
        float a = 0.f;
#pragma unroll
        for (int i = 0; i < 32; ++i) a += fr[i] * w[i];
        acc[cc] = a;
    }
    unsigned short* yr = yb + (long)n * 160 + c0;
#pragma unroll
    for (int qq = 0; qq < 5; ++qq) {
        unsigned int wlo = f2b(acc[2 * qq]);
        unsigned int whi = f2b(acc[2 * qq + 1]);
        ((unsigned int*)yr)[qq] = wlo | (whi << 16);
    }
}

// Fused iteration kernel, templated on nodes-per-32-lane-group (NPG = 4 or 8).
// Larger NPG amortizes the per-wave weight-table streaming (each wave reads
// the full 48KB of tables once regardless of NPG).
// gather_from_y: iter-1 gathers from the bf16 y table; else from fp32 msg_in.
// msg_out fp32 -> full-128B-line scatter writes (no L2 write-allocate).
template <int NPG>
__global__ __launch_bounds__(256) void k_conv_update(
    const float* __restrict__ msg_in, const int* __restrict__ row_ptr,
    const float4* __restrict__ rw4, const float* __restrict__ convb,
    const float4* __restrict__ wi4, const float* __restrict__ bi,
    const float* __restrict__ bh, const float4* __restrict__ nnw4,
    const float* __restrict__ nnb, const int* __restrict__ out_ptr,
    const int* __restrict__ oslot, const float4* __restrict__ oea,
    const unsigned short* __restrict__ yb, const int* __restrict__ esrc,
    const float4* __restrict__ eea,
    float* __restrict__ feat, float* __restrict__ msg_out,
    int gather_from_y, int write_msg) {
    constexpr int NH = NPG / 2;       // v2f pairs per group
    constexpr int NQ = NPG / 4;       // float4 quads per group
    constexpr int ROW = 8 * NPG + 4;  // LDS row stride (floats, 16B-aligned)
    __shared__ float fsT[32][ROW];    // [dim][node]
    __shared__ float msT[32][ROW];
    int t = threadIdx.x;
    int g = t >> 5, o = t & 31;
    int gc = g * NPG;
    int nb = blockIdx.x * (8 * NPG) + gc;
    float f[NPG], m[NPG];
    float cb = convb[o];
#pragma unroll
    for (int j = 0; j < NPG; ++j) {
        int n = nb + j;
        bool v = (n < NN);
        f[j] = v ? feat[n * 32 + o] : 0.f;
        m[j] = cb;
        if (v) {
            int e0 = row_ptr[n], e1 = row_ptr[n + 1];
            if (gather_from_y) {
                for (int e = e0; e < e1; ++e) {
                    int s = esrc[e];               // uniform across group
                    float4 a = eea[e];
                    const unsigned short* yr = yb + (long)s * 160;
                    float y0 = b2f(yr[o]);
                    float y1 = b2f(yr[32 + o]);
                    float y2 = b2f(yr[64 + o]);
                    float y3 = b2f(yr[96 + o]);
                    float y4 = b2f(yr[128 + o]);
                    m[j] += y4 + a.x * y0 + a.y * y1 + a.z * y2 + a.w * y3;
                }
            } else {
                for (int e = e0; e < e1; ++e)
                    m[j] += msg_in[(e << 5) + o];
            }
        }
    }
#pragma unroll
    for (int q = 0; q < NQ; ++q)
        *(float4*)&fsT[o][gc + 4 * q] =
            make_float4(f[4 * q], f[4 * q + 1], f[4 * q + 2], f[4 * q + 3]);
    __syncthreads();

    // phase ab: m_pre += f@root ; gh = f@wh  (rw4 = root|whr|whz|whn)
    float bhr = bh[o], bhz = bh[32 + o], bhn = bh[64 + o];
    v2f m2[NH], ghr2[NH], ghz2[NH], ghn2[NH];
#pragma unroll
    for (int h = 0; h < NH; ++h) {
        m2[h] = (v2f){m[2 * h], m[2 * h + 1]};
        ghr2[h] = (v2f){bhr, bhr};
        ghz2[h] = (v2f){bhz, bhz};
        ghn2[h] = (v2f){bhn, bhn};
    }
#pragma unroll 2
    for (int i = 0; i < 32; ++i) {
        float4 w = rw4[i * 32 + o];
        float4 fvq[NQ];
#pragma unroll
        for (int q = 0; q < NQ; ++q) fvq[q] = *(const float4*)&fsT[i][gc + 4 * q];
        v2f f2[NH];
#pragma unroll
        for (int q = 0; q < NQ; ++q) {
            f2[2 * q] = (v2f){fvq[q].x, fvq[q].y};
            f2[2 * q + 1] = (v2f){fvq[q].z, fvq[q].w};
        }
#pragma unroll
        for (int h = 0; h < NH; ++h) {
            m2[h] = fma2(f2[h], w.x, m2[h]);
            ghr2[h] = fma2(f2[h], w.y, ghr2[h]);
            ghz2[h] = fma2(f2[h], w.z, ghz2[h]);
            ghn2[h] = fma2(f2[h], w.w, ghn2[h]);
        }
    }
    float mm[NPG];
#pragma unroll
    for (int h = 0; h < NH; ++h) {
        mm[2 * h] = fmaxf(m2[h].x, 0.f);
        mm[2 * h + 1] = fmaxf(m2[h].y, 0.f);
    }
#pragma unroll
    for (int q = 0; q < NQ; ++q)
        *(float4*)&msT[o][gc + 4 * q] =
            make_float4(mm[4 * q], mm[4 * q + 1], mm[4 * q + 2], mm[4 * q + 3]);
    __syncthreads();

    // phase c: gi = m@wi
    float bir = bi[o], biz = bi[32 + o], bin_ = bi[64 + o];
    v2f gir2[NH], giz2[NH], gin2[NH];
#pragma unroll
    for (int h = 0; h < NH; ++h) {
        gir2[h] = (v2f){bir, bir};
        giz2[h] = (v2f){biz, biz};
        gin2[h] = (v2f){bin_, bin_};
    }
#pragma unroll 2
    for (int k = 0; k < 32; ++k) {
        float4 w = wi4[k * 32 + o];
        float4 mvq[NQ];
#pragma unroll
        for (int q = 0; q < NQ; ++q) mvq[q] = *(const float4*)&msT[k][gc + 4 * q];
        v2f p2[NH];
#pragma unroll
        for (int q = 0; q < NQ; ++q) {
            p2[2 * q] = (v2f){mvq[q].x, mvq[q].y};
            p2[2 * q + 1] = (v2f){mvq[q].z, mvq[q].w};
        }
#pragma unroll
        for (int h = 0; h < NH; ++h) {
            gir2[h] = fma2(p2[h], w.x, gir2[h]);
            giz2[h] = fma2(p2[h], w.y, giz2[h]);
            gin2[h] = fma2(p2[h], w.z, gin2[h]);
        }
    }
    float fn[NPG];
#pragma unroll
    for (int h = 0; h < NH; ++h) {
        float girA[2] = {gir2[h].x, gir2[h].y};
        float gizA[2] = {giz2[h].x, giz2[h].y};
        float ginA[2] = {gin2[h].x, gin2[h].y};
        float ghrA[2] = {ghr2[h].x, ghr2[h].y};
        float ghzA[2] = {ghz2[h].x, ghz2[h].y};
        float ghnA[2] = {ghn2[h].x, ghn2[h].y};
#pragma unroll
        for (int c = 0; c < 2; ++c) {
            int j = 2 * h + c;
            float r = 1.f / (1.f + __expf(-(girA[c] + ghrA[c])));
            float z = 1.f / (1.f + __expf(-(gizA[c] + ghzA[c])));
            float nt = tanhf(ginA[c] + r * ghnA[c]);
            fn[j] = (1.f - z) * nt + z * f[j];
            int n = nb + j;
            if (n < NN) feat[n * 32 + o] = fn[j];
        }
    }
    if (!write_msg) return;

    // ya phase: reuse fsT rows (same-wave write->read, lgkmcnt-ordered)
#pragma unroll
    for (int q = 0; q < NQ; ++q)
        *(float4*)&fsT[o][gc + 4 * q] =
            make_float4(fn[4 * q], fn[4 * q + 1], fn[4 * q + 2], fn[4 * q + 3]);
    v2f y0a[NH], y1a[NH], y2a[NH], y3a[NH], y4a[NH];
#pragma unroll
    for (int h = 0; h < NH; ++h) {
        y0a[h] = (v2f){0.f, 0.f}; y1a[h] = (v2f){0.f, 0.f};
        y2a[h] = (v2f){0.f, 0.f}; y3a[h] = (v2f){0.f, 0.f};
        y4a[h] = (v2f){0.f, 0.f};
    }
#pragma unroll 2
    for (int i = 0; i < 32; ++i) {
        float4 w = nnw4[i * 32 + o];      // nn_w row (i*32+o): q=0..3
        float w1 = nnb[i * 32 + o];
        float4 fvq[NQ];
#pragma unroll
        for (int q = 0; q < NQ; ++q) fvq[q] = *(const float4*)&fsT[i][gc + 4 * q];
        v2f f2[NH];
#pragma unroll
        for (int q = 0; q < NQ; ++q) {
            f2[2 * q] = (v2f){fvq[q].x, fvq[q].y};
            f2[2 * q + 1] = (v2f){fvq[q].z, fvq[q].w};
        }
#pragma unroll
        for (int h = 0; h < NH; ++h) {
            y0a[h] = fma2(f2[h], w.x, y0a[h]);
            y1a[h] = fma2(f2[h], w.y, y1a[h]);
            y2a[h] = fma2(f2[h], w.z, y2a[h]);
            y3a[h] = fma2(f2[h], w.w, y3a[h]);
            y4a[h] = fma2(f2[h], w1, y4a[h]);
        }
    }
    float ya0[NPG], ya1[NPG], ya2[NPG], ya3[NPG], ya4[NPG];
#pragma unroll
    for (int h = 0; h < NH; ++h) {
        ya0[2 * h] = y0a[h].x; ya0[2 * h + 1] = y0a[h].y;
        ya1[2 * h] = y1a[h].x; ya1[2 * h + 1] = y1a[h].y;
        ya2[2 * h] = y2a[h].x; ya2[2 * h + 1] = y2a[h].y;
        ya3[2 * h] = y3a[h].x; ya3[2 * h + 1] = y3a[h].y;
        ya4[2 * h] = y4a[h].x; ya4[2 * h + 1] = y4a[h].y;
    }
#pragma unroll
    for (int j = 0; j < NPG; ++j) {
        int n = nb + j;
        if (n < NN) {
            int p0 = out_ptr[n], p1 = out_ptr[n + 1];
            for (int p = p0; p < p1; ++p) {
                float4 a = oea[p];
                int slot = oslot[p];
                msg_out[(slot << 5) + o] =
                    ya4[j] + a.x * ya0[j] + a.y * ya1[j]
                           + a.z * ya2[j] + a.w * ya3[j];
            }
        }
    }
}

// Fused mean-pool + classifier
__global__ __launch_bounds__(64) void k_pool_final(
    const float* __restrict__ feat, const int* __restrict__ batch,
    const float* __restrict__ w, const float* __restrict__ b,
    float* __restrict__ out) {
    int g = blockIdx.x;
    int t = threadIdx.x;
    int o = t & 31, h = t >> 5;
    int lo = 0, hi = NN;
    while (lo < hi) { int mid = (lo + hi) >> 1; if (batch[mid] < g) lo = mid + 1; else hi = mid; }
    int start = lo;
    hi = NN;
    while (lo < hi) { int mid = (lo + hi) >> 1; if (batch[mid] <= g) lo = mid + 1; else hi = mid; }
    int end = lo;
    float acc = 0.f;
    for (int n = start + h; n < end; n += 2) acc += feat[(long)n * 32 + o];
    acc += __shfl_xor(acc, 32, 64);
    float p = acc / fmaxf((float)(end - start), 1.f);
    float l0 = p * w[o], l1 = p * w[32 + o];
#pragma unroll
    for (int s = 16; s >= 1; s >>= 1) {
        l0 += __shfl_xor(l0, s, 64);
        l1 += __shfl_xor(l1, s, 64);
    }
    if (t == 0) {
        l0 += b[0]; l1 += b[1];
        float mx = fmaxf(l0, l1);
        float lse = mx + logf(__expf(l0 - mx) + __expf(l1 - mx));
        out[g * 2 + 0] = l0 - lse;
        out[g * 2 + 1] = l1 - lse;
    }
}

extern "C" void kernel_launch(void* const* d_in, const int* in_sizes, int n_in,
                              void* d_out, int out_size, void* d_ws, size_t ws_size,
                              hipStream_t stream) {
    const float* x        = (const float*)d_in[0];
    const float* edge_attr= (const float*)d_in[1];
    const float* lin0_w   = (const float*)d_in[2];
    const float* lin0_b   = (const float*)d_in[3];
    const float* nn_w     = (const float*)d_in[4];
    const float* nn_b     = (const float*)d_in[5];
    const float* root_w   = (const float*)d_in[6];
    const float* conv_b   = (const float*)d_in[7];
    const float* gru_wi   = (const float*)d_in[8];
    const float* gru_wh   = (const float*)d_in[9];
    const float* gru_bi   = (const float*)d_in[10];
    const float* gru_bh   = (const float*)d_in[11];
    const float* lin1_w   = (const float*)d_in[12];
    const float* lin1_b   = (const float*)d_in[13];
    const int*   edge_idx = (const int*)d_in[14];
    const int*   batch    = (const int*)d_in[15];
    float* out = (float*)d_out;

    // layout: float4 tables first (16B alignment guaranteed at ws base)
    float4* rw4   = (float4*)d_ws;             // 1024
    float4* wi4   = rw4 + 1024;                // 1024
    float4* eea   = wi4 + 1024;                // EE
    float4* oea   = eea + EE;                  // EE
    float*  feat  = (float*)(oea + EE);        // N*32
    float*  Wre   = feat + (long)NN * 32;      // 5120
    int*    cnt   = (int*)(Wre + 5120);        // 2N
    int*    tmp   = cnt + 2 * NN;              // 2N
    int*    bsum  = tmp + 2 * NN;              // 512
    int*    row_ptr = bsum + 512;              // N+1
    int*    cursor  = row_ptr + NN + 1;        // N
    int*    out_ptr = cursor + NN;             // N+1
    int*    cursor2 = out_ptr + NN + 1;        // N
    int*    esrc  = cursor2 + NN;              // EE
    int*    oslot = esrc + EE;                 // EE
    unsigned short* yb = (unsigned short*)(oslot + EE);    // N*160 bf16
    // re-align to 16B for fp32 msg buffers
    size_t moff = ((size_t)((char*)(yb + (long)NN * 160) - (char*)d_ws) + 15) & ~(size_t)15;
    float*  msgA = (float*)((char*)d_ws + moff);           // E*32 f
    float*  msgB = msgA + (long)EE * 32;                   // E*32 f
    const float4* nnw4 = (const float4*)nn_w;  // [1024] rows of 4

    hipMemsetAsync(cnt, 0, 2 * NN * sizeof(int), stream);

    // init + weight tables + histogram (block-partitioned)
    k_setup<<<6250 + 28 + 391, 256, 0, stream>>>(x, lin0_w, lin0_b, nn_w, nn_b,
                                                 root_w, gru_wi, gru_wh, edge_idx,
                                                 feat, Wre, rw4, wi4, cnt);

    k_scan1<<<NB2, 256, 0, stream>>>(cnt, tmp, bsum);
    k_scan2<<<1, 512, 0, stream>>>(bsum);
    k_scan3<<<NB2, 256, 0, stream>>>(cnt, tmp, bsum, row_ptr, cursor, out_ptr, cursor2);

    // scatter + initial y (block-partitioned)
    k_scatter_y<<<391 + 782 * 4, 256, 0, stream>>>(edge_idx, edge_attr, cursor, cursor2,
                                                   esrc, eea, oslot, oea, feat, Wre, yb);

    // 3 fused iterations; iter1 gathers from y (NPG=4), iters 2-3 from fp32
    // msg with NPG=8 (2x weight-table amortization)
    k_conv_update<4><<<(NN + 31) / 32, 256, 0, stream>>>(
        msgA, row_ptr, rw4, conv_b, wi4, gru_bi, gru_bh, nnw4, nn_b,
        out_ptr, oslot, oea, yb, esrc, eea, feat, msgB, 1, 1);
    k_conv_update<8><<<(NN + 63) / 64, 256, 0, stream>>>(
        msgB, row_ptr, rw4, conv_b, wi4, gru_bi, gru_bh, nnw4, nn_b,
        out_ptr, oslot, oea, yb, esrc, eea, feat, msgA, 0, 1);
    k_conv_update<8><<<(NN + 63) / 64, 256, 0, stream>>>(
        msgA, row_ptr, rw4, conv_b, wi4, gru_bi, gru_bh, nnw4, nn_b,
        out_ptr, oslot, oea, yb, esrc, eea, feat, msgB, 0, 0);

    k_pool_final<<<GG, 64, 0, stream>>>(feat, batch, lin1_w, lin1_b, out);
}